// Round 2
// baseline (290.284 us; speedup 1.0000x reference)
//
#include <hip/hip_runtime.h>
#include <hip/hip_bf16.h>

#define B_GR   16
#define N_PER  1024
#define M_PER  4096
#define NVEC   64
#define FDIM   192      // 3*NVEC
#define FSKIP  64
#define HID    256
#define ODIM   128
#define N_TOT  (B_GR * N_PER)   // 16384
#define M_TOT  (B_GR * M_PER)   // 65536

// ---------------------------------------------------------------------------
// Kernel 1: KNN (K=3) of fine points among coarse points of the same batch.
// Ranking uses qq + pn - 2*q.p (matches reference's top_k input formula);
// weights use the exact (diff*diff).sum() like the reference's second pass.
// ---------------------------------------------------------------------------
__global__ __launch_bounds__(256) void knn_kernel(
    const float* __restrict__ pos,        // [N_TOT,3]
    const float* __restrict__ pos_skip,   // [M_TOT,3]
    int*   __restrict__ idx_out,          // [M_TOT,3] global indices
    float* __restrict__ w_out)            // [M_TOT,3]
{
    __shared__ float px0[N_PER], px1[N_PER], px2[N_PER], pn[N_PER];
    const int b = blockIdx.x >> 4;                 // 16 blocks per batch
    const int m = blockIdx.x * 256 + threadIdx.x;  // query index

    for (int j = threadIdx.x; j < N_PER; j += 256) {
        const float* p = pos + (size_t)(b * N_PER + j) * 3;
        float a0 = p[0], a1 = p[1], a2 = p[2];
        px0[j] = a0; px1[j] = a1; px2[j] = a2;
        pn[j] = a0*a0 + a1*a1 + a2*a2;
    }
    __syncthreads();

    const float* q = pos_skip + (size_t)m * 3;
    const float qx = q[0], qy = q[1], qz = q[2];
    const float qq = qx*qx + qy*qy + qz*qz;

    float d0 = 1e30f, d1 = 1e30f, d2 = 1e30f;
    int   i0 = 0,     i1 = 0,     i2 = 0;
    for (int j = 0; j < N_PER; ++j) {
        float r = qq + pn[j] - 2.0f * (qx*px0[j] + qy*px1[j] + qz*px2[j]);
        // strict < keeps earlier (lower) index on ties, matching lax.top_k
        if (r < d2) {
            if (r < d1) {
                d2 = d1; i2 = i1;
                if (r < d0) { d1 = d0; i1 = i0; d0 = r; i0 = j; }
                else        { d1 = r;  i1 = j; }
            } else { d2 = r; i2 = j; }
        }
    }

    int sel[3] = {i0, i1, i2};
    #pragma unroll
    for (int k = 0; k < 3; ++k) {
        int j = sel[k];
        float dx = px0[j] - qx, dy = px1[j] - qy, dz = px2[j] - qz;
        float sqd = dx*dx + dy*dy + dz*dz;
        idx_out[m*3 + k] = b * N_PER + j;
        w_out[m*3 + k]   = 1.0f / fmaxf(sqd, 1e-16f);
    }
}

// ---------------------------------------------------------------------------
// Kernel 2: fused edge-transform + 2-layer MLP.
// Block = 256 threads (4 waves), 64 rows (fine points) per block.
// h tile [64][256] f32 lives in LDS (64 KB) with an XOR swizzle on word-index
// bits 2..4 keyed by (row>>3)&7 so scalar column-writes (phase A) and float4
// k-slice reads (phases B/C) are both bank-conflict-free.
// ---------------------------------------------------------------------------
__device__ __forceinline__ int hword(int r, int c) {
    return r * 256 + (c ^ (((r >> 3) & 7) << 2));
}

__global__ __launch_bounds__(256) void fused_kernel(
    const float* __restrict__ x,             // [N_TOT,192]
    const float* __restrict__ x_skip,        // [M_TOT,64]
    const float* __restrict__ lframes,       // [N_TOT,3,3]
    const float* __restrict__ lframes_skip,  // [M_TOT,3,3]
    const float* __restrict__ W1,            // [256,256]
    const float* __restrict__ b1,            // [256]
    const float* __restrict__ W2,            // [256,128]
    const float* __restrict__ b2,            // [128]
    const int*   __restrict__ idx_in,        // [M_TOT,3]
    const float* __restrict__ w_in,          // [M_TOT,3]
    float* __restrict__ out)                 // [M_TOT,128]
{
    __shared__ __align__(16) float hbuf[64 * 256];   // 64 KB

    const int tid  = threadIdx.x;
    const int lane = tid & 63;
    const int wv   = tid >> 6;
    const int blk  = blockIdx.x;

    // ---------------- Phase A: build h = [y | x_skip] ----------------
    for (int rr = 0; rr < 16; ++rr) {
        const int r = wv * 16 + rr;
        const int m = blk * 64 + r;
        const int e = m * 3;
        const int nb0 = idx_in[e], nb1 = idx_in[e+1], nb2 = idx_in[e+2];
        const float w0 = w_in[e], w1 = w_in[e+1], w2 = w_in[e+2];
        const float inv_den = 1.0f / (w0 + w1 + w2);

        float Ry[9];
        #pragma unroll
        for (int t = 0; t < 9; ++t) Ry[t] = lframes_skip[(size_t)m*9 + t];

        const int   nb[3] = {nb0, nb1, nb2};
        const float wk[3] = {w0, w1, w2};
        float U[3][9];
        #pragma unroll
        for (int k = 0; k < 3; ++k) {
            float Rx[9];
            #pragma unroll
            for (int t = 0; t < 9; ++t) Rx[t] = lframes[(size_t)nb[k]*9 + t];
            #pragma unroll
            for (int a = 0; a < 3; ++a)
                #pragma unroll
                for (int c = 0; c < 3; ++c)
                    U[k][a*3+c] = Ry[a*3+0]*Rx[c*3+0]
                                + Ry[a*3+1]*Rx[c*3+1]
                                + Ry[a*3+2]*Rx[c*3+2];
        }

        float n0 = 0.f, n1 = 0.f, n2 = 0.f;
        #pragma unroll
        for (int k = 0; k < 3; ++k) {
            const float* xp = x + (size_t)nb[k]*FDIM + lane*3;
            const float v0 = xp[0], v1 = xp[1], v2 = xp[2];
            n0 += wk[k]*(U[k][0]*v0 + U[k][1]*v1 + U[k][2]*v2);
            n1 += wk[k]*(U[k][3]*v0 + U[k][4]*v1 + U[k][5]*v2);
            n2 += wk[k]*(U[k][6]*v0 + U[k][7]*v1 + U[k][8]*v2);
        }
        hbuf[hword(r, lane*3+0)] = n0 * inv_den;
        hbuf[hword(r, lane*3+1)] = n1 * inv_den;
        hbuf[hword(r, lane*3+2)] = n2 * inv_den;
        hbuf[hword(r, 192+lane)] = x_skip[(size_t)m*FSKIP + lane];
    }
    __syncthreads();

    // ---------------- Phase B: hidden = relu(h @ W1 + b1) ----------------
    const int rg  = tid & 7;     // 8 row-groups of 8 rows
    const int cg  = tid >> 3;    // 32 col-groups of 8 cols
    const int swz = rg << 2;     // ((r>>3)&7)<<2 for r = rg*8+i

    float acc[8][8];
    #pragma unroll
    for (int i = 0; i < 8; ++i)
        #pragma unroll
        for (int j = 0; j < 8; ++j) acc[i][j] = 0.f;

    for (int k0 = 0; k0 < 256; k0 += 4) {
        float hfv[8][4];
        #pragma unroll
        for (int i = 0; i < 8; ++i) {
            float4 t = *reinterpret_cast<const float4*>(
                &hbuf[(rg*8+i)*256 + (k0 ^ swz)]);
            hfv[i][0]=t.x; hfv[i][1]=t.y; hfv[i][2]=t.z; hfv[i][3]=t.w;
        }
        float wfv[4][8];
        #pragma unroll
        for (int kk = 0; kk < 4; ++kk) {
            const float* wp = W1 + (size_t)(k0+kk)*HID + cg*8;
            float4 a = *reinterpret_cast<const float4*>(wp);
            float4 b = *reinterpret_cast<const float4*>(wp+4);
            wfv[kk][0]=a.x; wfv[kk][1]=a.y; wfv[kk][2]=a.z; wfv[kk][3]=a.w;
            wfv[kk][4]=b.x; wfv[kk][5]=b.y; wfv[kk][6]=b.z; wfv[kk][7]=b.w;
        }
        #pragma unroll
        for (int kk = 0; kk < 4; ++kk)
            #pragma unroll
            for (int i = 0; i < 8; ++i)
                #pragma unroll
                for (int j = 0; j < 8; ++j)
                    acc[i][j] += hfv[i][kk] * wfv[kk][j];
    }
    __syncthreads();   // all reads of h done before overwrite

    {
        float bj[8];
        #pragma unroll
        for (int j = 0; j < 8; ++j) bj[j] = b1[cg*8 + j];
        #pragma unroll
        for (int i = 0; i < 8; ++i) {
            const int r = rg*8 + i;
            #pragma unroll
            for (int j4 = 0; j4 < 2; ++j4) {
                float4 v;
                v.x = fmaxf(acc[i][j4*4+0] + bj[j4*4+0], 0.f);
                v.y = fmaxf(acc[i][j4*4+1] + bj[j4*4+1], 0.f);
                v.z = fmaxf(acc[i][j4*4+2] + bj[j4*4+2], 0.f);
                v.w = fmaxf(acc[i][j4*4+3] + bj[j4*4+3], 0.f);
                *reinterpret_cast<float4*>(
                    &hbuf[r*256 + ((cg*8 + j4*4) ^ swz)]) = v;
            }
        }
    }
    __syncthreads();

    // ---------------- Phase C: out = hidden @ W2 + b2 ----------------
    float acc2[8][4];
    #pragma unroll
    for (int i = 0; i < 8; ++i)
        #pragma unroll
        for (int j = 0; j < 4; ++j) acc2[i][j] = 0.f;

    for (int k0 = 0; k0 < 256; k0 += 4) {
        float hfv[8][4];
        #pragma unroll
        for (int i = 0; i < 8; ++i) {
            float4 t = *reinterpret_cast<const float4*>(
                &hbuf[(rg*8+i)*256 + (k0 ^ swz)]);
            hfv[i][0]=t.x; hfv[i][1]=t.y; hfv[i][2]=t.z; hfv[i][3]=t.w;
        }
        float wfv[4][4];
        #pragma unroll
        for (int kk = 0; kk < 4; ++kk) {
            float4 t = *reinterpret_cast<const float4*>(
                W2 + (size_t)(k0+kk)*ODIM + cg*4);
            wfv[kk][0]=t.x; wfv[kk][1]=t.y; wfv[kk][2]=t.z; wfv[kk][3]=t.w;
        }
        #pragma unroll
        for (int kk = 0; kk < 4; ++kk)
            #pragma unroll
            for (int i = 0; i < 8; ++i)
                #pragma unroll
                for (int j = 0; j < 4; ++j)
                    acc2[i][j] += hfv[i][kk] * wfv[kk][j];
    }

    {
        float bj[4];
        #pragma unroll
        for (int j = 0; j < 4; ++j) bj[j] = b2[cg*4 + j];
        #pragma unroll
        for (int i = 0; i < 8; ++i) {
            const int m = blk*64 + rg*8 + i;
            float4 v;
            v.x = acc2[i][0] + bj[0];
            v.y = acc2[i][1] + bj[1];
            v.z = acc2[i][2] + bj[2];
            v.w = acc2[i][3] + bj[3];
            *reinterpret_cast<float4*>(&out[(size_t)m*ODIM + cg*4]) = v;
        }
    }
}

// ---------------------------------------------------------------------------
// Kernel 3: pass-through tuple tail: pos_skip, batch_skip (int32 -> float),
// lframes_skip.  NOTE: JAX default config downcasts int64 -> int32, so
// batch_skip arrives as int32 (harness: integer -> const int*).
// ---------------------------------------------------------------------------
__global__ __launch_bounds__(256) void tail_kernel(
    const float* __restrict__ pos_skip,
    const int*   __restrict__ batch_skip,
    const float* __restrict__ lframes_skip,
    float* __restrict__ dst)
{
    const int i = blockIdx.x * 256 + threadIdx.x;
    const int P = M_TOT * 3;
    const int Q = P + M_TOT;
    const int R = Q + M_TOT * 9;
    if (i < P)      dst[i] = pos_skip[i];
    else if (i < Q) dst[i] = (float)batch_skip[i - P];
    else if (i < R) dst[i] = lframes_skip[i - Q];
}

extern "C" void kernel_launch(void* const* d_in, const int* in_sizes, int n_in,
                              void* d_out, int out_size, void* d_ws, size_t ws_size,
                              hipStream_t stream) {
    const float* x            = (const float*)d_in[0];
    const float* pos          = (const float*)d_in[1];
    const float* pos_skip     = (const float*)d_in[2];
    const float* x_skip       = (const float*)d_in[3];
    const float* lframes      = (const float*)d_in[4];
    const float* lframes_skip = (const float*)d_in[5];
    const float* W1           = (const float*)d_in[6];
    const float* b1           = (const float*)d_in[7];
    const float* W2           = (const float*)d_in[8];
    const float* b2           = (const float*)d_in[9];
    const int*   batch_skip   = (const int*)d_in[11];

    int*   idxb = (int*)d_ws;
    float* wb   = (float*)((char*)d_ws + (size_t)M_TOT * 3 * sizeof(int));
    float* out  = (float*)d_out;

    knn_kernel<<<M_TOT/256, 256, 0, stream>>>(pos, pos_skip, idxb, wb);

    fused_kernel<<<M_TOT/64, 256, 0, stream>>>(x, x_skip, lframes, lframes_skip,
                                               W1, b1, W2, b2, idxb, wb, out);

    float* tail = out + (size_t)M_TOT * ODIM;
    const int tail_elems = M_TOT * (3 + 1 + 9);
    tail_kernel<<<(tail_elems + 255)/256, 256, 0, stream>>>(
        pos_skip, batch_skip, lframes_skip, tail);
}

// Round 3
// 182.636 us; speedup vs baseline: 1.5894x; 1.5894x over previous
//
#include <hip/hip_runtime.h>
#include <hip/hip_bf16.h>

#define B_GR   16
#define N_PER  1024
#define M_PER  4096
#define NVEC   64
#define FDIM   192      // 3*NVEC
#define FSKIP  64
#define HID    256
#define ODIM   128
#define N_TOT  (B_GR * N_PER)   // 16384
#define M_TOT  (B_GR * M_PER)   // 65536

typedef __attribute__((ext_vector_type(8))) short short8v;   // 8 bf16 = 4 VGPR
typedef __attribute__((ext_vector_type(4))) float f32x4;     // MFMA acc

__device__ __forceinline__ unsigned short f2bf(float f) {
    __hip_bfloat16 h = __float2bfloat16(f);   // RNE
    return *reinterpret_cast<unsigned short*>(&h);
}

// swizzled element index into a [64][256] bf16 row-major LDS tile.
// XOR of elem bits 3..5 with row&7 keeps 8-elem (16B) chunks contiguous and
// spreads the stride-512B fragment reads across 8 distinct 16B slots.
__device__ __forceinline__ int hsw(int r, int e) {
    return r * 256 + (e ^ ((r & 7) << 3));
}

// ---------------------------------------------------------------------------
// Kernel 0: weight prep — W1 [256,256] f32 -> W1T bf16 [c][k] (k contiguous),
//           W2 [256,128] f32 -> W2T bf16 [c][k].  B-fragment-friendly layout.
// ---------------------------------------------------------------------------
__global__ __launch_bounds__(256) void wprep_kernel(
    const float* __restrict__ W1, const float* __restrict__ W2,
    unsigned short* __restrict__ wt1, unsigned short* __restrict__ wt2)
{
    const int i = blockIdx.x * 256 + threadIdx.x;
    if (i < 256 * 256) {
        const int k = i >> 8, c = i & 255;       // read coalesced over c
        wt1[c * 256 + k] = f2bf(W1[i]);
    } else {
        const int j = i - 256 * 256;
        const int k = j >> 7, c = j & 127;
        wt2[c * 256 + k] = f2bf(W2[j]);
    }
}

// ---------------------------------------------------------------------------
// Kernel 1: KNN (K=3). Ranking formula matches reference top_k input
// (qq + pn - 2 q.p). Candidates cached in LDS as float4 (x,y,z,|p|^2).
// ---------------------------------------------------------------------------
__global__ __launch_bounds__(256) void knn_kernel(
    const float* __restrict__ pos,        // [N_TOT,3]
    const float* __restrict__ pos_skip,   // [M_TOT,3]
    int*   __restrict__ idx_out)          // [M_TOT,3] global indices
{
    __shared__ float4 pc[N_PER];          // 16 KB
    const int b = blockIdx.x >> 4;                 // 16 blocks per batch
    const int m = blockIdx.x * 256 + threadIdx.x;  // query index

    for (int j = threadIdx.x; j < N_PER; j += 256) {
        const float* p = pos + (size_t)(b * N_PER + j) * 3;
        float a0 = p[0], a1 = p[1], a2 = p[2];
        pc[j] = make_float4(a0, a1, a2, a0*a0 + a1*a1 + a2*a2);
    }
    __syncthreads();

    const float* q = pos_skip + (size_t)m * 3;
    const float qx = q[0], qy = q[1], qz = q[2];
    const float qq = qx*qx + qy*qy + qz*qz;

    float d0 = 1e30f, d1 = 1e30f, d2 = 1e30f;
    int   i0 = 0,     i1 = 0,     i2 = 0;
    #pragma unroll 4
    for (int j = 0; j < N_PER; ++j) {
        float4 c = pc[j];
        float r = (qq + c.w) - 2.0f * (qx*c.x + qy*c.y + qz*c.z);
        if (r < d2) {                       // strict <: lower index wins ties
            if (r < d1) {
                d2 = d1; i2 = i1;
                if (r < d0) { d1 = d0; i1 = i0; d0 = r; i0 = j; }
                else        { d1 = r;  i1 = j; }
            } else { d2 = r; i2 = j; }
        }
    }
    idx_out[m*3 + 0] = b * N_PER + i0;
    idx_out[m*3 + 1] = b * N_PER + i1;
    idx_out[m*3 + 2] = b * N_PER + i2;
}

// ---------------------------------------------------------------------------
// Kernel 2: fused edge-transform + MFMA MLP.
// 256 threads (4 waves), 64 rows per block. h tile [64][256] bf16 in LDS
// (32 KB, hsw swizzle); same buffer reused for hidden (barrier-separated).
// GEMM1: each wave = 64 rows x 64 cols (4x4 16x16 frags, K=256).
// GEMM2: each wave = 64 rows x 32 cols (4x2 frags, K=256).
// A/B fragments: 8 contiguous-K bf16/lane (row|col = lane&15, k-group =
// lane>>4), C/D: col = lane&15, row = (lane>>4)*4 + reg  [m89/m92-verified].
// ---------------------------------------------------------------------------
__global__ __launch_bounds__(256, 3) void fused_kernel(
    const float* __restrict__ x,             // [N_TOT,192]
    const float* __restrict__ pos,           // [N_TOT,3]
    const float* __restrict__ pos_skip,      // [M_TOT,3]
    const float* __restrict__ x_skip,        // [M_TOT,64]
    const float* __restrict__ lframes,       // [N_TOT,3,3]
    const float* __restrict__ lframes_skip,  // [M_TOT,3,3]
    const unsigned short* __restrict__ wt1,  // [256][256] bf16 (c-major)
    const float* __restrict__ b1,            // [256]
    const unsigned short* __restrict__ wt2,  // [128][256] bf16 (c-major)
    const float* __restrict__ b2,            // [128]
    const int*   __restrict__ idx_in,        // [M_TOT,3]
    float* __restrict__ out)                 // [M_TOT,128]
{
    __shared__ __align__(16) unsigned short hb[64 * 256];   // 32 KB

    const int tid  = threadIdx.x;
    const int lane = tid & 63;
    const int wv   = tid >> 6;
    const int blk  = blockIdx.x;
    const int lo   = lane & 15;
    const int hi   = lane >> 4;

    // ---------------- Phase A: build h = [y | x_skip] (bf16) ----------------
    for (int rr = 0; rr < 16; ++rr) {
        const int r = wv * 16 + rr;
        const int m = blk * 64 + r;
        const int e = m * 3;
        const int nb0 = idx_in[e], nb1 = idx_in[e+1], nb2 = idx_in[e+2];

        const float qx = pos_skip[e], qy = pos_skip[e+1], qz = pos_skip[e+2];
        const int nb[3] = {nb0, nb1, nb2};
        float wk[3];
        #pragma unroll
        for (int k = 0; k < 3; ++k) {
            const float* pp = pos + (size_t)nb[k] * 3;
            float dx = pp[0]-qx, dy = pp[1]-qy, dz = pp[2]-qz;
            wk[k] = 1.0f / fmaxf(dx*dx + dy*dy + dz*dz, 1e-16f);
        }
        const float inv_den = 1.0f / (wk[0] + wk[1] + wk[2]);

        float Ry[9];
        #pragma unroll
        for (int t = 0; t < 9; ++t) Ry[t] = lframes_skip[(size_t)m*9 + t];

        float U[3][9];
        #pragma unroll
        for (int k = 0; k < 3; ++k) {
            float Rx[9];
            #pragma unroll
            for (int t = 0; t < 9; ++t) Rx[t] = lframes[(size_t)nb[k]*9 + t];
            #pragma unroll
            for (int a = 0; a < 3; ++a)
                #pragma unroll
                for (int c = 0; c < 3; ++c)
                    U[k][a*3+c] = Ry[a*3+0]*Rx[c*3+0]
                                + Ry[a*3+1]*Rx[c*3+1]
                                + Ry[a*3+2]*Rx[c*3+2];
        }

        float n0 = 0.f, n1 = 0.f, n2 = 0.f;
        #pragma unroll
        for (int k = 0; k < 3; ++k) {
            const float* xp = x + (size_t)nb[k]*FDIM + lane*3;
            const float v0 = xp[0], v1 = xp[1], v2 = xp[2];
            n0 += wk[k]*(U[k][0]*v0 + U[k][1]*v1 + U[k][2]*v2);
            n1 += wk[k]*(U[k][3]*v0 + U[k][4]*v1 + U[k][5]*v2);
            n2 += wk[k]*(U[k][6]*v0 + U[k][7]*v1 + U[k][8]*v2);
        }
        hb[hsw(r, lane*3+0)] = f2bf(n0 * inv_den);
        hb[hsw(r, lane*3+1)] = f2bf(n1 * inv_den);
        hb[hsw(r, lane*3+2)] = f2bf(n2 * inv_den);
        hb[hsw(r, 192+lane)] = f2bf(x_skip[(size_t)m*FSKIP + lane]);
    }
    __syncthreads();

    // ---------------- GEMM1: hidden = relu(h @ W1 + b1) ----------------
    f32x4 acc[4][4];
    #pragma unroll
    for (int fi = 0; fi < 4; ++fi)
        #pragma unroll
        for (int ci = 0; ci < 4; ++ci) acc[fi][ci] = (f32x4)0.f;

    for (int ks = 0; ks < 8; ++ks) {
        const int kk = ks*32 + hi*8;
        short8v a[4], bf[4];
        #pragma unroll
        for (int fi = 0; fi < 4; ++fi) {
            const int r = fi*16 + lo;
            a[fi] = *reinterpret_cast<const short8v*>(
                &hb[r*256 + (kk ^ ((lo & 7) << 3))]);
        }
        #pragma unroll
        for (int ci = 0; ci < 4; ++ci) {
            const int cb = wv*64 + ci*16 + lo;
            bf[ci] = *reinterpret_cast<const short8v*>(&wt1[cb*256 + kk]);
        }
        #pragma unroll
        for (int fi = 0; fi < 4; ++fi)
            #pragma unroll
            for (int ci = 0; ci < 4; ++ci)
                acc[fi][ci] = __builtin_amdgcn_mfma_f32_16x16x32_bf16(
                    a[fi], bf[ci], acc[fi][ci], 0, 0, 0);
    }
    __syncthreads();   // all GEMM1 reads of h complete

    {
        float b1v[4];
        #pragma unroll
        for (int ci = 0; ci < 4; ++ci) b1v[ci] = b1[wv*64 + ci*16 + lo];
        #pragma unroll
        for (int fi = 0; fi < 4; ++fi)
            #pragma unroll
            for (int ci = 0; ci < 4; ++ci)
                #pragma unroll
                for (int q = 0; q < 4; ++q) {
                    const int r = fi*16 + hi*4 + q;
                    const int c = wv*64 + ci*16 + lo;
                    hb[hsw(r, c)] = f2bf(fmaxf(acc[fi][ci][q] + b1v[ci], 0.f));
                }
    }
    __syncthreads();

    // ---------------- GEMM2: out = hidden @ W2 + b2 ----------------
    f32x4 acc2[4][2];
    #pragma unroll
    for (int fi = 0; fi < 4; ++fi)
        #pragma unroll
        for (int ci = 0; ci < 2; ++ci) acc2[fi][ci] = (f32x4)0.f;

    for (int ks = 0; ks < 8; ++ks) {
        const int kk = ks*32 + hi*8;
        short8v a[4], bf[2];
        #pragma unroll
        for (int fi = 0; fi < 4; ++fi) {
            const int r = fi*16 + lo;
            a[fi] = *reinterpret_cast<const short8v*>(
                &hb[r*256 + (kk ^ ((lo & 7) << 3))]);
        }
        #pragma unroll
        for (int ci = 0; ci < 2; ++ci) {
            const int cb = wv*32 + ci*16 + lo;
            bf[ci] = *reinterpret_cast<const short8v*>(&wt2[cb*256 + kk]);
        }
        #pragma unroll
        for (int fi = 0; fi < 4; ++fi)
            #pragma unroll
            for (int ci = 0; ci < 2; ++ci)
                acc2[fi][ci] = __builtin_amdgcn_mfma_f32_16x16x32_bf16(
                    a[fi], bf[ci], acc2[fi][ci], 0, 0, 0);
    }

    {
        float b2v[2];
        #pragma unroll
        for (int ci = 0; ci < 2; ++ci) b2v[ci] = b2[wv*32 + ci*16 + lo];
        #pragma unroll
        for (int fi = 0; fi < 4; ++fi)
            #pragma unroll
            for (int ci = 0; ci < 2; ++ci)
                #pragma unroll
                for (int q = 0; q < 4; ++q) {
                    const int r = fi*16 + hi*4 + q;
                    const int c = wv*32 + ci*16 + lo;
                    out[(size_t)(blk*64 + r)*ODIM + c] = acc2[fi][ci][q] + b2v[ci];
                }
    }
}

// ---------------------------------------------------------------------------
// Kernel 3: pass-through tail: pos_skip, batch_skip (int32), lframes_skip
// ---------------------------------------------------------------------------
__global__ __launch_bounds__(256) void tail_kernel(
    const float* __restrict__ pos_skip,
    const int*   __restrict__ batch_skip,
    const float* __restrict__ lframes_skip,
    float* __restrict__ dst)
{
    const int i = blockIdx.x * 256 + threadIdx.x;
    const int P = M_TOT * 3;
    const int Q = P + M_TOT;
    const int R = Q + M_TOT * 9;
    if (i < P)      dst[i] = pos_skip[i];
    else if (i < Q) dst[i] = (float)batch_skip[i - P];
    else if (i < R) dst[i] = lframes_skip[i - Q];
}

extern "C" void kernel_launch(void* const* d_in, const int* in_sizes, int n_in,
                              void* d_out, int out_size, void* d_ws, size_t ws_size,
                              hipStream_t stream) {
    const float* x            = (const float*)d_in[0];
    const float* pos          = (const float*)d_in[1];
    const float* pos_skip     = (const float*)d_in[2];
    const float* x_skip       = (const float*)d_in[3];
    const float* lframes      = (const float*)d_in[4];
    const float* lframes_skip = (const float*)d_in[5];
    const float* W1           = (const float*)d_in[6];
    const float* b1           = (const float*)d_in[7];
    const float* W2           = (const float*)d_in[8];
    const float* b2           = (const float*)d_in[9];
    const int*   batch_skip   = (const int*)d_in[11];

    char* ws = (char*)d_ws;
    int*            idxb = (int*)ws;                              // 786432 B
    unsigned short* wt1  = (unsigned short*)(ws + 786432);        // 131072 B
    unsigned short* wt2  = (unsigned short*)(ws + 786432 + 131072); // 65536 B
    float* out = (float*)d_out;

    wprep_kernel<<<(256*256 + 256*128) / 256, 256, 0, stream>>>(W1, W2, wt1, wt2);
    knn_kernel<<<M_TOT/256, 256, 0, stream>>>(pos, pos_skip, idxb);

    fused_kernel<<<M_TOT/64, 256, 0, stream>>>(x, pos, pos_skip, x_skip,
                                               lframes, lframes_skip,
                                               wt1, b1, wt2, b2, idxb, out);

    float* tail = out + (size_t)M_TOT * ODIM;
    const int tail_elems = M_TOT * (3 + 1 + 9);
    tail_kernel<<<(tail_elems + 255)/256, 256, 0, stream>>>(
        pos_skip, batch_skip, lframes_skip, tail);
}

// Round 4
// 85.719 us; speedup vs baseline: 3.3865x; 2.1306x over previous
//
#include <hip/hip_runtime.h>
#include <hip/hip_bf16.h>

#define B_GR   16
#define N_PER  1024
#define M_PER  4096
#define NVEC   64
#define FDIM   192      // 3*NVEC
#define FSKIP  64
#define HID    256
#define ODIM   128
#define N_TOT  (B_GR * N_PER)   // 16384
#define M_TOT  (B_GR * M_PER)   // 65536

typedef __attribute__((ext_vector_type(8))) short short8v;   // 8 bf16 = 4 VGPR
typedef __attribute__((ext_vector_type(4))) float f32x4;     // MFMA acc

__device__ __forceinline__ unsigned short f2bf(float f) {
    __hip_bfloat16 h = __float2bfloat16(f);   // RNE
    return *reinterpret_cast<unsigned short*>(&h);
}

// swizzled element index into a [64][256] bf16 row-major LDS tile.
// XOR of elem bits 3..5 with row&7 keeps 8-elem (16B) chunks contiguous and
// spreads the stride-512B fragment reads across 8 distinct 16B slots.
__device__ __forceinline__ int hsw(int r, int e) {
    return r * 256 + (e ^ ((r & 7) << 3));
}

// ---------------------------------------------------------------------------
// Kernel 0: weight prep — W1 [256,256] f32 -> bf16 [c][k] (k contiguous),
//           W2 [256,128] f32 -> bf16 [c][k].  B-fragment-friendly layout.
// ---------------------------------------------------------------------------
__global__ __launch_bounds__(256) void wprep_kernel(
    const float* __restrict__ W1, const float* __restrict__ W2,
    unsigned short* __restrict__ wt1, unsigned short* __restrict__ wt2)
{
    const int i = blockIdx.x * 256 + threadIdx.x;
    if (i < 256 * 256) {
        const int k = i >> 8, c = i & 255;       // read coalesced over c
        wt1[c * 256 + k] = f2bf(W1[i]);
    } else {
        const int j = i - 256 * 256;
        const int k = j >> 7, c = j & 127;
        wt2[c * 256 + k] = f2bf(W2[j]);
    }
}

// ---------------------------------------------------------------------------
// Kernel 1: fully fused KNN + edge-transform + MFMA MLP.
// 256 threads (4 waves), 64 rows (queries) per block; 64 blocks per batch.
// Phase K: 4 lanes per query scan interleaved quarters of the 1024
//          candidates (branchless top-3), then shfl_xor lexicographic merge
//          (exact lax.top_k tie-break: lower index wins on equal distance).
// Phase A: frame transform + weighted mean -> h tile [64][256] bf16 in LDS.
// GEMM1/GEMM2: 16x16x32 bf16 MFMA, fragments per m89/m92-verified layout.
// Candidate cache (16 KB) unions with the h tile (32 KB).
// ---------------------------------------------------------------------------
__global__ __launch_bounds__(256, 4) void fused_kernel(
    const float* __restrict__ x,             // [N_TOT,192]
    const float* __restrict__ pos,           // [N_TOT,3]
    const float* __restrict__ pos_skip,      // [M_TOT,3]
    const float* __restrict__ x_skip,        // [M_TOT,64]
    const float* __restrict__ lframes,       // [N_TOT,3,3]
    const float* __restrict__ lframes_skip,  // [M_TOT,3,3]
    const unsigned short* __restrict__ wt1,  // [256][256] bf16 (c-major)
    const float* __restrict__ b1,            // [256]
    const unsigned short* __restrict__ wt2,  // [128][256] bf16 (c-major)
    const float* __restrict__ b2,            // [128]
    float* __restrict__ out)                 // [M_TOT,128]
{
    __shared__ __align__(16) char smraw[64 * 256 * 2];   // 32 KB union
    __shared__ int   idxL[64 * 3];
    __shared__ float wL[64 * 3];

    float4*         pc = reinterpret_cast<float4*>(smraw);          // [1024]
    unsigned short* hb = reinterpret_cast<unsigned short*>(smraw);  // [64*256]

    const int tid  = threadIdx.x;
    const int lane = tid & 63;
    const int wv   = tid >> 6;
    const int blk  = blockIdx.x;
    const int lo   = lane & 15;
    const int hi   = lane >> 4;
    const int b    = blk >> 6;               // 64 blocks per batch

    // ---------------- Phase K: KNN for this block's 64 queries ----------------
    #pragma unroll
    for (int k = 0; k < 4; ++k) {
        const int j = tid + k * 256;
        const float* p = pos + (size_t)(b * N_PER + j) * 3;
        float a0 = p[0], a1 = p[1], a2 = p[2];
        pc[j] = make_float4(a0, a1, a2, a0*a0 + a1*a1 + a2*a2);
    }
    __syncthreads();

    {
        const int q   = tid >> 2;            // query row 0..63
        const int sub = tid & 3;
        const int m   = blk * 64 + q;
        const float qx = pos_skip[m*3+0], qy = pos_skip[m*3+1], qz = pos_skip[m*3+2];
        const float qq = qx*qx + qy*qy + qz*qz;

        float d0 = 1e30f, d1 = 1e30f, d2 = 1e30f;
        int   i0 = 0,     i1 = 0,     i2 = 0;
        #pragma unroll 4
        for (int t = 0; t < 256; ++t) {
            const int j = t*4 + sub;         // interleaved: wave reads 64B bcast
            float4 c = pc[j];
            float r = (qq + c.w) - 2.0f * (qx*c.x + qy*c.y + qz*c.z);
            bool c0 = r < d0, c1 = r < d1, c2 = r < d2;
            i2 = c2 ? (c1 ? i1 : j) : i2;
            i1 = c1 ? (c0 ? i0 : j) : i1;
            i0 = c0 ? j : i0;
            d2 = c2 ? (c1 ? d1 : r) : d2;
            d1 = c1 ? (c0 ? d0 : r) : d1;
            d0 = c0 ? r : d0;
        }
        // butterfly merge across the 4 sublanes, lexicographic (d, j)
        #pragma unroll
        for (int mask = 1; mask <= 2; mask <<= 1) {
            float e0 = __shfl_xor(d0, mask), e1 = __shfl_xor(d1, mask),
                  e2 = __shfl_xor(d2, mask);
            int   j0 = __shfl_xor(i0, mask), j1 = __shfl_xor(i1, mask),
                  j2 = __shfl_xor(i2, mask);
            const float ee[3] = {e0, e1, e2};
            const int   jj[3] = {j0, j1, j2};
            #pragma unroll
            for (int s = 0; s < 3; ++s) {
                const float e = ee[s]; const int j = jj[s];
                bool c0 = (e < d0) || (e == d0 && j < i0);
                bool c1 = (e < d1) || (e == d1 && j < i1);
                bool c2 = (e < d2) || (e == d2 && j < i2);
                i2 = c2 ? (c1 ? i1 : j) : i2;
                i1 = c1 ? (c0 ? i0 : j) : i1;
                i0 = c0 ? j : i0;
                d2 = c2 ? (c1 ? d1 : e) : d2;
                d1 = c1 ? (c0 ? d0 : e) : d1;
                d0 = c0 ? e : d0;
            }
        }
        // exact weights (reference recomputes diff*diff on selected neighbors)
        if (sub < 3) {
            const int jl = (sub == 0) ? i0 : (sub == 1) ? i1 : i2;
            float4 c = pc[jl];
            float dx = c.x - qx, dy = c.y - qy, dz = c.z - qz;
            float sqd = dx*dx + dy*dy + dz*dz;
            wL[q*3 + sub]   = 1.0f / fmaxf(sqd, 1e-16f);
            idxL[q*3 + sub] = b * N_PER + jl;
        }
    }
    __syncthreads();   // pc dead below; wL/idxL visible; hb reuses pc space

    // ---------------- Phase A: build h = [y | x_skip] (bf16) ----------------
    for (int rr = 0; rr < 16; ++rr) {
        const int r = wv * 16 + rr;
        const int m = blk * 64 + r;
        const int nb[3] = {idxL[r*3+0], idxL[r*3+1], idxL[r*3+2]};
        const float wk[3] = {wL[r*3+0], wL[r*3+1], wL[r*3+2]};
        const float inv_den = 1.0f / (wk[0] + wk[1] + wk[2]);

        float Ry[9];
        #pragma unroll
        for (int t = 0; t < 9; ++t) Ry[t] = lframes_skip[(size_t)m*9 + t];

        float U[3][9];
        #pragma unroll
        for (int k = 0; k < 3; ++k) {
            float Rx[9];
            #pragma unroll
            for (int t = 0; t < 9; ++t) Rx[t] = lframes[(size_t)nb[k]*9 + t];
            #pragma unroll
            for (int a = 0; a < 3; ++a)
                #pragma unroll
                for (int c = 0; c < 3; ++c)
                    U[k][a*3+c] = Ry[a*3+0]*Rx[c*3+0]
                                + Ry[a*3+1]*Rx[c*3+1]
                                + Ry[a*3+2]*Rx[c*3+2];
        }

        float n0 = 0.f, n1 = 0.f, n2 = 0.f;
        #pragma unroll
        for (int k = 0; k < 3; ++k) {
            const float* xp = x + (size_t)nb[k]*FDIM + lane*3;
            const float v0 = xp[0], v1 = xp[1], v2 = xp[2];
            n0 += wk[k]*(U[k][0]*v0 + U[k][1]*v1 + U[k][2]*v2);
            n1 += wk[k]*(U[k][3]*v0 + U[k][4]*v1 + U[k][5]*v2);
            n2 += wk[k]*(U[k][6]*v0 + U[k][7]*v1 + U[k][8]*v2);
        }
        hb[hsw(r, lane*3+0)] = f2bf(n0 * inv_den);
        hb[hsw(r, lane*3+1)] = f2bf(n1 * inv_den);
        hb[hsw(r, lane*3+2)] = f2bf(n2 * inv_den);
        hb[hsw(r, 192+lane)] = f2bf(x_skip[(size_t)m*FSKIP + lane]);
    }
    __syncthreads();

    // ---------------- GEMM1: hidden = relu(h @ W1 + b1) ----------------
    f32x4 acc[4][4];
    #pragma unroll
    for (int fi = 0; fi < 4; ++fi)
        #pragma unroll
        for (int ci = 0; ci < 4; ++ci) acc[fi][ci] = (f32x4)0.f;

    for (int ks = 0; ks < 8; ++ks) {
        const int kk = ks*32 + hi*8;
        short8v a[4], bf[4];
        #pragma unroll
        for (int fi = 0; fi < 4; ++fi) {
            const int r = fi*16 + lo;
            a[fi] = *reinterpret_cast<const short8v*>(
                &hb[r*256 + (kk ^ ((lo & 7) << 3))]);
        }
        #pragma unroll
        for (int ci = 0; ci < 4; ++ci) {
            const int cb = wv*64 + ci*16 + lo;
            bf[ci] = *reinterpret_cast<const short8v*>(&wt1[cb*256 + kk]);
        }
        #pragma unroll
        for (int fi = 0; fi < 4; ++fi)
            #pragma unroll
            for (int ci = 0; ci < 4; ++ci)
                acc[fi][ci] = __builtin_amdgcn_mfma_f32_16x16x32_bf16(
                    a[fi], bf[ci], acc[fi][ci], 0, 0, 0);
    }
    __syncthreads();   // all GEMM1 reads of h complete

    {
        float b1v[4];
        #pragma unroll
        for (int ci = 0; ci < 4; ++ci) b1v[ci] = b1[wv*64 + ci*16 + lo];
        #pragma unroll
        for (int fi = 0; fi < 4; ++fi)
            #pragma unroll
            for (int ci = 0; ci < 4; ++ci)
                #pragma unroll
                for (int q = 0; q < 4; ++q) {
                    const int r = fi*16 + hi*4 + q;
                    const int c = wv*64 + ci*16 + lo;
                    hb[hsw(r, c)] = f2bf(fmaxf(acc[fi][ci][q] + b1v[ci], 0.f));
                }
    }
    __syncthreads();

    // ---------------- GEMM2: out = hidden @ W2 + b2 ----------------
    f32x4 acc2[4][2];
    #pragma unroll
    for (int fi = 0; fi < 4; ++fi)
        #pragma unroll
        for (int ci = 0; ci < 2; ++ci) acc2[fi][ci] = (f32x4)0.f;

    for (int ks = 0; ks < 8; ++ks) {
        const int kk = ks*32 + hi*8;
        short8v a[4], bf[2];
        #pragma unroll
        for (int fi = 0; fi < 4; ++fi) {
            const int r = fi*16 + lo;
            a[fi] = *reinterpret_cast<const short8v*>(
                &hb[r*256 + (kk ^ ((lo & 7) << 3))]);
        }
        #pragma unroll
        for (int ci = 0; ci < 2; ++ci) {
            const int cb = wv*32 + ci*16 + lo;
            bf[ci] = *reinterpret_cast<const short8v*>(&wt2[cb*256 + kk]);
        }
        #pragma unroll
        for (int fi = 0; fi < 4; ++fi)
            #pragma unroll
            for (int ci = 0; ci < 2; ++ci)
                acc2[fi][ci] = __builtin_amdgcn_mfma_f32_16x16x32_bf16(
                    a[fi], bf[ci], acc2[fi][ci], 0, 0, 0);
    }

    {
        float b2v[2];
        #pragma unroll
        for (int ci = 0; ci < 2; ++ci) b2v[ci] = b2[wv*32 + ci*16 + lo];
        #pragma unroll
        for (int fi = 0; fi < 4; ++fi)
            #pragma unroll
            for (int ci = 0; ci < 2; ++ci)
                #pragma unroll
                for (int q = 0; q < 4; ++q) {
                    const int r = fi*16 + hi*4 + q;
                    const int c = wv*32 + ci*16 + lo;
                    out[(size_t)(blk*64 + r)*ODIM + c] = acc2[fi][ci][q] + b2v[ci];
                }
    }
}

// ---------------------------------------------------------------------------
// Kernel 2: pass-through tail: pos_skip, batch_skip (int32), lframes_skip
// ---------------------------------------------------------------------------
__global__ __launch_bounds__(256) void tail_kernel(
    const float* __restrict__ pos_skip,
    const int*   __restrict__ batch_skip,
    const float* __restrict__ lframes_skip,
    float* __restrict__ dst)
{
    const int i = blockIdx.x * 256 + threadIdx.x;
    const int P = M_TOT * 3;
    const int Q = P + M_TOT;
    const int R = Q + M_TOT * 9;
    if (i < P)      dst[i] = pos_skip[i];
    else if (i < Q) dst[i] = (float)batch_skip[i - P];
    else if (i < R) dst[i] = lframes_skip[i - Q];
}

extern "C" void kernel_launch(void* const* d_in, const int* in_sizes, int n_in,
                              void* d_out, int out_size, void* d_ws, size_t ws_size,
                              hipStream_t stream) {
    const float* x            = (const float*)d_in[0];
    const float* pos          = (const float*)d_in[1];
    const float* pos_skip     = (const float*)d_in[2];
    const float* x_skip       = (const float*)d_in[3];
    const float* lframes      = (const float*)d_in[4];
    const float* lframes_skip = (const float*)d_in[5];
    const float* W1           = (const float*)d_in[6];
    const float* b1           = (const float*)d_in[7];
    const float* W2           = (const float*)d_in[8];
    const float* b2           = (const float*)d_in[9];
    const int*   batch_skip   = (const int*)d_in[11];

    char* ws = (char*)d_ws;
    unsigned short* wt1 = (unsigned short*)ws;                 // 131072 B
    unsigned short* wt2 = (unsigned short*)(ws + 131072);      // 65536 B
    float* out = (float*)d_out;

    wprep_kernel<<<(256*256 + 256*128) / 256, 256, 0, stream>>>(W1, W2, wt1, wt2);

    fused_kernel<<<M_TOT/64, 256, 0, stream>>>(x, pos, pos_skip, x_skip,
                                               lframes, lframes_skip,
                                               wt1, b1, wt2, b2, out);

    float* tail = out + (size_t)M_TOT * ODIM;
    const int tail_elems = M_TOT * (3 + 1 + 9);
    tail_kernel<<<(tail_elems + 255)/256, 256, 0, stream>>>(
        pos_skip, batch_skip, lframes_skip, tail);
}

// Round 5
// 78.529 us; speedup vs baseline: 3.6965x; 1.0916x over previous
//
#include <hip/hip_runtime.h>
#include <hip/hip_bf16.h>

#define B_GR   16
#define N_PER  1024
#define M_PER  4096
#define NVEC   64
#define FDIM   192      // 3*NVEC
#define FSKIP  64
#define HID    256
#define ODIM   128
#define N_TOT  (B_GR * N_PER)   // 16384
#define M_TOT  (B_GR * M_PER)   // 65536

typedef __attribute__((ext_vector_type(8))) short short8v;   // 8 bf16 = 4 VGPR
typedef __attribute__((ext_vector_type(4))) float f32x4;     // MFMA acc

__device__ __forceinline__ unsigned short f2bf(float f) {
    __hip_bfloat16 h = __float2bfloat16(f);   // RNE
    return *reinterpret_cast<unsigned short*>(&h);
}

// swizzled element index into a [64][256] bf16 row-major LDS tile.
// XOR of elem bits 3..5 with row&7 keeps 8-elem (16B) chunks contiguous and
// spreads the stride-512B fragment reads across 8 distinct 16B slots.
__device__ __forceinline__ int hsw(int r, int e) {
    return r * 256 + (e ^ ((r & 7) << 3));
}

// ---------------------------------------------------------------------------
// Kernel 0: weight prep — W1 [256,256] f32 -> bf16 [c][k] (k contiguous),
//           W2 [256,128] f32 -> bf16 [c][k].  B-fragment-friendly layout.
// ---------------------------------------------------------------------------
__global__ __launch_bounds__(256) void wprep_kernel(
    const float* __restrict__ W1, const float* __restrict__ W2,
    unsigned short* __restrict__ wt1, unsigned short* __restrict__ wt2)
{
    const int i = blockIdx.x * 256 + threadIdx.x;
    if (i < 256 * 256) {
        const int k = i >> 8, c = i & 255;       // read coalesced over c
        wt1[c * 256 + k] = f2bf(W1[i]);
    } else {
        const int j = i - 256 * 256;
        const int k = j >> 7, c = j & 127;
        wt2[c * 256 + k] = f2bf(W2[j]);
    }
}

// ---------------------------------------------------------------------------
// Kernel 1: fully fused KNN + edge-transform + MFMA MLP.
// 512 threads (8 waves), 64 rows (queries) per block; 64 blocks per batch.
// Phase K: 8 lanes per query scan interleaved eighths of 1024 candidates
//          (branchless top-3), 3-level shfl_xor lexicographic merge
//          (exact lax.top_k tie-break: lower index wins on equal distance).
// Phase U: one thread per (row, neighbor) computes U = Ry Rx^T pre-scaled by
//          wk/sum(w) -> Usc[64][28] f32 in LDS (computed ONCE, not per lane).
// Phase A: transform = 27 FMA/row/lane using broadcast float4 reads of Usc.
// GEMM1/GEMM2: 16x16x32 bf16 MFMA split over 8 waves (32/16-col slices).
// Candidate cache (16 KB) unions with the h tile (32 KB). LDS ~41.5 KB ->
// 3 blocks/CU x 8 waves = 24 waves/CU theoretical.
// ---------------------------------------------------------------------------
__global__ __launch_bounds__(512, 5) void fused_kernel(
    const float* __restrict__ x,             // [N_TOT,192]
    const float* __restrict__ pos,           // [N_TOT,3]
    const float* __restrict__ pos_skip,      // [M_TOT,3]
    const float* __restrict__ x_skip,        // [M_TOT,64]
    const float* __restrict__ lframes,       // [N_TOT,3,3]
    const float* __restrict__ lframes_skip,  // [M_TOT,3,3]
    const unsigned short* __restrict__ wt1,  // [256][256] bf16 (c-major)
    const float* __restrict__ b1,            // [256]
    const unsigned short* __restrict__ wt2,  // [128][256] bf16 (c-major)
    const float* __restrict__ b2,            // [128]
    float* __restrict__ out)                 // [M_TOT,128]
{
    __shared__ __align__(16) char smraw[64 * 256 * 2];   // 32 KB: pc ∪ hb
    __shared__ __align__(16) float Usc[64 * 28];         // 7 KB scaled-U table
    __shared__ int   idxL[64 * 3];
    __shared__ float wL[64 * 3];

    float4*         pc = reinterpret_cast<float4*>(smraw);          // [1024]
    unsigned short* hb = reinterpret_cast<unsigned short*>(smraw);  // [64*256]

    const int tid  = threadIdx.x;
    const int lane = tid & 63;
    const int wv   = tid >> 6;               // 0..7
    const int blk  = blockIdx.x;
    const int lo   = lane & 15;
    const int hi   = lane >> 4;
    const int b    = blk >> 6;               // 64 blocks per batch

    // ---------------- Phase K: candidate cache + top-3 scan ----------------
    #pragma unroll
    for (int k = 0; k < 2; ++k) {
        const int j = tid + k * 512;
        const float* p = pos + (size_t)(b * N_PER + j) * 3;
        float a0 = p[0], a1 = p[1], a2 = p[2];
        pc[j] = make_float4(a0, a1, a2, a0*a0 + a1*a1 + a2*a2);
    }
    __syncthreads();

    {
        const int q   = tid >> 3;            // query row 0..63
        const int sub = tid & 7;
        const int m   = blk * 64 + q;
        const float qx = pos_skip[m*3+0], qy = pos_skip[m*3+1], qz = pos_skip[m*3+2];
        const float qq = qx*qx + qy*qy + qz*qz;

        float d0 = 1e30f, d1 = 1e30f, d2 = 1e30f;
        int   i0 = 0,     i1 = 0,     i2 = 0;
        #pragma unroll 4
        for (int t = 0; t < 128; ++t) {
            const int j = t*8 + sub;         // wave reads 128B bcast x8
            float4 c = pc[j];
            float r = (qq + c.w) - 2.0f * (qx*c.x + qy*c.y + qz*c.z);
            bool c0 = r < d0, c1 = r < d1, c2 = r < d2;
            i2 = c2 ? (c1 ? i1 : j) : i2;
            i1 = c1 ? (c0 ? i0 : j) : i1;
            i0 = c0 ? j : i0;
            d2 = c2 ? (c1 ? d1 : r) : d2;
            d1 = c1 ? (c0 ? d0 : r) : d1;
            d0 = c0 ? r : d0;
        }
        // butterfly merge across the 8 sublanes, lexicographic (d, j)
        #pragma unroll
        for (int mask = 1; mask <= 4; mask <<= 1) {
            float e0 = __shfl_xor(d0, mask), e1 = __shfl_xor(d1, mask),
                  e2 = __shfl_xor(d2, mask);
            int   j0 = __shfl_xor(i0, mask), j1 = __shfl_xor(i1, mask),
                  j2 = __shfl_xor(i2, mask);
            const float ee[3] = {e0, e1, e2};
            const int   jj[3] = {j0, j1, j2};
            #pragma unroll
            for (int s = 0; s < 3; ++s) {
                const float e = ee[s]; const int j = jj[s];
                bool c0 = (e < d0) || (e == d0 && j < i0);
                bool c1 = (e < d1) || (e == d1 && j < i1);
                bool c2 = (e < d2) || (e == d2 && j < i2);
                i2 = c2 ? (c1 ? i1 : j) : i2;
                i1 = c1 ? (c0 ? i0 : j) : i1;
                i0 = c0 ? j : i0;
                d2 = c2 ? (c1 ? d1 : e) : d2;
                d1 = c1 ? (c0 ? d0 : e) : d1;
                d0 = c0 ? e : d0;
            }
        }
        // exact weights (reference recomputes diff*diff on selected neighbors)
        if (sub < 3) {
            const int jl = (sub == 0) ? i0 : (sub == 1) ? i1 : i2;
            float4 c = pc[jl];
            float dx = c.x - qx, dy = c.y - qy, dz = c.z - qz;
            float sqd = dx*dx + dy*dy + dz*dz;
            wL[q*3 + sub]   = 1.0f / fmaxf(sqd, 1e-16f);
            idxL[q*3 + sub] = b * N_PER + jl;
        }
    }
    __syncthreads();   // pc dead below; wL/idxL visible

    // ---------------- Phase U: scaled frame-change matrices (once) ----------
    {
        const int q = tid >> 3, sub = tid & 7;
        if (sub < 3) {
            const int m  = blk * 64 + q;
            const int nb = idxL[q*3 + sub];
            const float w0 = wL[q*3+0], w1 = wL[q*3+1], w2 = wL[q*3+2];
            const float s  = wL[q*3+sub] / (w0 + w1 + w2);   // wk/den folded in

            float RyS[9], Rx[9];
            #pragma unroll
            for (int t = 0; t < 9; ++t) RyS[t] = s * lframes_skip[(size_t)m*9 + t];
            #pragma unroll
            for (int t = 0; t < 9; ++t) Rx[t] = lframes[(size_t)nb*9 + t];

            float* dst = &Usc[q*28 + sub*9];
            #pragma unroll
            for (int a = 0; a < 3; ++a)
                #pragma unroll
                for (int c = 0; c < 3; ++c)
                    dst[a*3+c] = RyS[a*3+0]*Rx[c*3+0]
                               + RyS[a*3+1]*Rx[c*3+1]
                               + RyS[a*3+2]*Rx[c*3+2];
        }
    }
    __syncthreads();

    // ---------------- Phase A: build h = [y | x_skip] (bf16) ----------------
    for (int rr = 0; rr < 8; ++rr) {
        const int r = wv * 8 + rr;
        const int m = blk * 64 + r;
        const int nbs[3] = {idxL[r*3+0], idxL[r*3+1], idxL[r*3+2]};

        float Ub[28];
        float4* Ub4 = reinterpret_cast<float4*>(Ub);
        #pragma unroll
        for (int t = 0; t < 7; ++t)
            Ub4[t] = *reinterpret_cast<const float4*>(&Usc[r*28 + t*4]);  // bcast

        float n0 = 0.f, n1 = 0.f, n2 = 0.f;
        #pragma unroll
        for (int k = 0; k < 3; ++k) {
            const float* xp = x + (size_t)nbs[k]*FDIM + lane*3;
            const float v0 = xp[0], v1 = xp[1], v2 = xp[2];
            const int o = k*9;
            n0 += Ub[o+0]*v0 + Ub[o+1]*v1 + Ub[o+2]*v2;
            n1 += Ub[o+3]*v0 + Ub[o+4]*v1 + Ub[o+5]*v2;
            n2 += Ub[o+6]*v0 + Ub[o+7]*v1 + Ub[o+8]*v2;
        }
        hb[hsw(r, lane*3+0)] = f2bf(n0);
        hb[hsw(r, lane*3+1)] = f2bf(n1);
        hb[hsw(r, lane*3+2)] = f2bf(n2);
        hb[hsw(r, 192+lane)] = f2bf(x_skip[(size_t)m*FSKIP + lane]);
    }
    __syncthreads();

    // ---------------- GEMM1: hidden = relu(h @ W1 + b1) ----------------
    // wave wv covers cols [wv*32, wv*32+32)
    f32x4 acc[4][2];
    #pragma unroll
    for (int fi = 0; fi < 4; ++fi)
        #pragma unroll
        for (int ci = 0; ci < 2; ++ci) acc[fi][ci] = (f32x4)0.f;

    for (int ks = 0; ks < 8; ++ks) {
        const int kk = ks*32 + hi*8;
        short8v a[4], bf[2];
        #pragma unroll
        for (int fi = 0; fi < 4; ++fi) {
            const int r = fi*16 + lo;
            a[fi] = *reinterpret_cast<const short8v*>(
                &hb[r*256 + (kk ^ ((lo & 7) << 3))]);
        }
        #pragma unroll
        for (int ci = 0; ci < 2; ++ci) {
            const int cb = wv*32 + ci*16 + lo;
            bf[ci] = *reinterpret_cast<const short8v*>(&wt1[cb*256 + kk]);
        }
        #pragma unroll
        for (int fi = 0; fi < 4; ++fi)
            #pragma unroll
            for (int ci = 0; ci < 2; ++ci)
                acc[fi][ci] = __builtin_amdgcn_mfma_f32_16x16x32_bf16(
                    a[fi], bf[ci], acc[fi][ci], 0, 0, 0);
    }
    __syncthreads();   // all GEMM1 reads of h complete

    {
        float b1v[2];
        #pragma unroll
        for (int ci = 0; ci < 2; ++ci) b1v[ci] = b1[wv*32 + ci*16 + lo];
        #pragma unroll
        for (int fi = 0; fi < 4; ++fi)
            #pragma unroll
            for (int ci = 0; ci < 2; ++ci)
                #pragma unroll
                for (int q = 0; q < 4; ++q) {
                    const int r = fi*16 + hi*4 + q;
                    const int c = wv*32 + ci*16 + lo;
                    hb[hsw(r, c)] = f2bf(fmaxf(acc[fi][ci][q] + b1v[ci], 0.f));
                }
    }
    __syncthreads();

    // ---------------- GEMM2: out = hidden @ W2 + b2 ----------------
    // wave wv covers cols [wv*16, wv*16+16)
    f32x4 acc2[4];
    #pragma unroll
    for (int fi = 0; fi < 4; ++fi) acc2[fi] = (f32x4)0.f;

    for (int ks = 0; ks < 8; ++ks) {
        const int kk = ks*32 + hi*8;
        short8v a[4], bf;
        #pragma unroll
        for (int fi = 0; fi < 4; ++fi) {
            const int r = fi*16 + lo;
            a[fi] = *reinterpret_cast<const short8v*>(
                &hb[r*256 + (kk ^ ((lo & 7) << 3))]);
        }
        {
            const int cb = wv*16 + lo;
            bf = *reinterpret_cast<const short8v*>(&wt2[cb*256 + kk]);
        }
        #pragma unroll
        for (int fi = 0; fi < 4; ++fi)
            acc2[fi] = __builtin_amdgcn_mfma_f32_16x16x32_bf16(
                a[fi], bf, acc2[fi], 0, 0, 0);
    }

    {
        const float b2v = b2[wv*16 + lo];
        #pragma unroll
        for (int fi = 0; fi < 4; ++fi)
            #pragma unroll
            for (int q = 0; q < 4; ++q) {
                const int r = fi*16 + hi*4 + q;
                const int c = wv*16 + lo;
                out[(size_t)(blk*64 + r)*ODIM + c] = acc2[fi][q] + b2v;
            }
    }
}

// ---------------------------------------------------------------------------
// Kernel 2: pass-through tail: pos_skip, batch_skip (int32), lframes_skip
// ---------------------------------------------------------------------------
__global__ __launch_bounds__(256) void tail_kernel(
    const float* __restrict__ pos_skip,
    const int*   __restrict__ batch_skip,
    const float* __restrict__ lframes_skip,
    float* __restrict__ dst)
{
    const int i = blockIdx.x * 256 + threadIdx.x;
    const int P = M_TOT * 3;
    const int Q = P + M_TOT;
    const int R = Q + M_TOT * 9;
    if (i < P)      dst[i] = pos_skip[i];
    else if (i < Q) dst[i] = (float)batch_skip[i - P];
    else if (i < R) dst[i] = lframes_skip[i - Q];
}

extern "C" void kernel_launch(void* const* d_in, const int* in_sizes, int n_in,
                              void* d_out, int out_size, void* d_ws, size_t ws_size,
                              hipStream_t stream) {
    const float* x            = (const float*)d_in[0];
    const float* pos          = (const float*)d_in[1];
    const float* pos_skip     = (const float*)d_in[2];
    const float* x_skip       = (const float*)d_in[3];
    const float* lframes      = (const float*)d_in[4];
    const float* lframes_skip = (const float*)d_in[5];
    const float* W1           = (const float*)d_in[6];
    const float* b1           = (const float*)d_in[7];
    const float* W2           = (const float*)d_in[8];
    const float* b2           = (const float*)d_in[9];
    const int*   batch_skip   = (const int*)d_in[11];

    char* ws = (char*)d_ws;
    unsigned short* wt1 = (unsigned short*)ws;                 // 131072 B
    unsigned short* wt2 = (unsigned short*)(ws + 131072);      // 65536 B
    float* out = (float*)d_out;

    wprep_kernel<<<(256*256 + 256*128) / 256, 256, 0, stream>>>(W1, W2, wt1, wt2);

    fused_kernel<<<M_TOT/64, 512, 0, stream>>>(x, pos, pos_skip, x_skip,
                                               lframes, lframes_skip,
                                               wt1, b1, wt2, b2, out);

    float* tail = out + (size_t)M_TOT * ODIM;
    const int tail_elems = M_TOT * (3 + 1 + 9);
    tail_kernel<<<(tail_elems + 255)/256, 256, 0, stream>>>(
        pos_skip, batch_skip, lframes_skip, tail);
}